// Round 8
// baseline (222.435 us; speedup 1.0000x reference)
//
#include <hip/hip_runtime.h>

#define N_NODES 150000
#define N_EDGES 2400000
#define F_IN    22
#define HID     32
#define N_CLS   6
#define BN_EPS  1e-5f

#define BSHIFT  8
#define BMASK   255
#define NB      ((N_NODES + BMASK) >> BSHIFT)       // 586 buckets of 256 nodes
#define NBLK_BIN 256                                // one bin block per CU
#define CHUNK   ((N_EDGES + NBLK_BIN - 1) / NBLK_BIN)   // 9375 edges per block
#define CHUNK_H 8192
#define NBLK_H  ((N_EDGES + CHUNK_H - 1) / CHUNK_H) // 293 hist blocks
#define NBLK_EMB ((N_NODES + 255) / 256)            // 586 embed blocks
#define NREP    8                                   // stats replicas

// bf16 round-to-nearest-even, packed storage helpers
__device__ __forceinline__ unsigned bf16rne(float f) {
    unsigned u = __float_as_uint(f);
    return (u + 0x7FFFu + ((u >> 16) & 1u)) >> 16;
}
__device__ __forceinline__ float bflo(unsigned p) { return __uint_as_float(p << 16); }
__device__ __forceinline__ float bfhi(unsigned p) { return __uint_as_float(p & 0xFFFF0000u); }

// ---------------------------------------------------------------------------
// K0 (fused): blocks [0,NBLK_EMB) -> per-node h = relu(x@W_emb+b_emb)@W_gcn,
//             stored as packed bf16 (16 uints per node row).
//             blocks [NBLK_EMB, NBLK_EMB+NBLK_H) -> bucket histogram of dst
// ---------------------------------------------------------------------------
__global__ void embed_hist_kernel(const float* __restrict__ x,
                                  const float* __restrict__ W_emb,
                                  const float* __restrict__ b_emb,
                                  const float* __restrict__ W_gcn,
                                  unsigned* __restrict__ hb,
                                  const int* __restrict__ dst,
                                  int* __restrict__ bcnt) {
    if (blockIdx.x < NBLK_EMB) {
        __shared__ float sWe[F_IN * HID];
        __shared__ float sbe[HID];
        __shared__ float sWg[HID * HID];
        for (int t = threadIdx.x; t < F_IN * HID; t += blockDim.x) sWe[t] = W_emb[t];
        if (threadIdx.x < HID) sbe[threadIdx.x] = b_emb[threadIdx.x];
        for (int t = threadIdx.x; t < HID * HID; t += blockDim.x) sWg[t] = W_gcn[t];
        __syncthreads();

        int i = blockIdx.x * blockDim.x + threadIdx.x;
        if (i >= N_NODES) return;

        float xi[F_IN];
#pragma unroll
        for (int f = 0; f < F_IN; ++f) xi[f] = x[(size_t)i * F_IN + f];

        float h1[HID];
#pragma unroll
        for (int j = 0; j < HID; ++j) {
            float acc = sbe[j];
#pragma unroll
            for (int f = 0; f < F_IN; ++f) acc = fmaf(xi[f], sWe[f * HID + j], acc);
            h1[j] = fmaxf(acc, 0.0f);
        }
#pragma unroll
        for (int jj = 0; jj < HID / 2; ++jj) {
            float a0 = 0.0f, a1 = 0.0f;
#pragma unroll
            for (int f = 0; f < HID; ++f) {
                a0 = fmaf(h1[f], sWg[f * HID + 2 * jj], a0);
                a1 = fmaf(h1[f], sWg[f * HID + 2 * jj + 1], a1);
            }
            hb[(size_t)i * 16 + jj] = bf16rne(a0) | (bf16rne(a1) << 16);
        }
    } else {
        __shared__ int hloc[NB];
        for (int t = threadIdx.x; t < NB; t += 256) hloc[t] = 0;
        __syncthreads();
        int base = (blockIdx.x - NBLK_EMB) * CHUNK_H;
        int end = base + CHUNK_H; if (end > N_EDGES) end = N_EDGES;
        for (int i = base + threadIdx.x; i < end; i += 256)
            atomicAdd(&hloc[dst[i] >> BSHIFT], 1);
        __syncthreads();
        for (int t = threadIdx.x; t < NB; t += 256)
            if (hloc[t]) atomicAdd(&bcnt[t], hloc[t]);
    }
}

// ---------------------------------------------------------------------------
// K1: single-block exclusive scan of NB (=586) bucket counts -> boff, bcur
// ---------------------------------------------------------------------------
__global__ void bucket_scan_kernel(const int* __restrict__ bcnt,
                                   int* __restrict__ boff,
                                   int* __restrict__ bcur) {
    __shared__ int s[1024];
    int t = threadIdx.x;
    int v0 = (t < NB) ? bcnt[t] : 0;
    s[t] = v0;
    __syncthreads();
#pragma unroll
    for (int o = 1; o < 1024; o <<= 1) {
        int v = (t >= o) ? s[t - o] : 0;
        __syncthreads();
        s[t] += v;                 // inclusive
        __syncthreads();
    }
    if (t < NB) {
        int e = s[t] - v0;         // exclusive
        boff[t] = e;
        bcur[t] = e;
    }
    if (t == NB - 1) boff[NB] = s[t];   // == N_EDGES
}

// ---------------------------------------------------------------------------
// K2: binned append, 256 blocks (one per CU, balanced), 512 threads.
//     LDS hist of the chunk -> one global atomic per touched bucket to
//     reserve a range -> packed writes (~64 B runs per (block,bucket)).
//     packed = (dst & 255) << 24 | src   (src < 2^24)
// ---------------------------------------------------------------------------
__global__ void bin_edges_kernel(const int* __restrict__ src,
                                 const int* __restrict__ dst,
                                 int* __restrict__ bcur,
                                 unsigned int* __restrict__ binned) {
    __shared__ int hloc[NB];
    __shared__ int base[NB];
    __shared__ int lcur[NB];
    for (int t = threadIdx.x; t < NB; t += 512) hloc[t] = 0;
    __syncthreads();

    int cbase = blockIdx.x * CHUNK;
    int cend = cbase + CHUNK; if (cend > N_EDGES) cend = N_EDGES;
    for (int i = cbase + threadIdx.x; i < cend; i += 512)
        atomicAdd(&hloc[dst[i] >> BSHIFT], 1);
    __syncthreads();
    for (int t = threadIdx.x; t < NB; t += 512) {
        int c = hloc[t];
        base[t] = c ? atomicAdd(&bcur[t], c) : 0;
        lcur[t] = 0;
    }
    __syncthreads();
    for (int i = cbase + threadIdx.x; i < cend; i += 512) {
        int d = dst[i];
        int b = d >> BSHIFT;
        int r = atomicAdd(&lcur[b], 1);
        binned[base[b] + r] = ((unsigned)(d & BMASK) << 24) | (unsigned)src[i];
    }
}

// ---------------------------------------------------------------------------
// K3: per-bucket local counting sort -> fully dst-sorted sorted_src + off[],
//     plus dis = rsqrt(1+deg).  Writes stay in this bucket's 16 KB window.
// ---------------------------------------------------------------------------
__global__ void bucket_csr_kernel(const int* __restrict__ boff,
                                  const unsigned int* __restrict__ binned,
                                  int* __restrict__ sorted_src,
                                  int* __restrict__ off,
                                  float* __restrict__ dis) {
    __shared__ int s_cnt[256];
    __shared__ int s_scan[256];
    __shared__ int s_cur[256];
    int b = blockIdx.x;
    int t = threadIdx.x;
    int s0 = boff[b], s1 = boff[b + 1];
    int nbase = b << BSHIFT;
    int nnode = N_NODES - nbase; if (nnode > 256) nnode = 256;

    s_cnt[t] = 0;
    __syncthreads();
    for (int k = s0 + t; k < s1; k += 256)
        atomicAdd(&s_cnt[binned[k] >> 24], 1);
    __syncthreads();

    int v = s_cnt[t];
    s_scan[t] = v;
    __syncthreads();
#pragma unroll
    for (int o = 1; o < 256; o <<= 1) {
        int u = (t >= o) ? s_scan[t - o] : 0;
        __syncthreads();
        s_scan[t] += u;            // inclusive
        __syncthreads();
    }
    int excl = s_scan[t] - v;
    s_cur[t] = excl;
    if (t < nnode) {
        off[nbase + t] = s0 + excl;
        dis[nbase + t] = rsqrtf(1.0f + (float)v);
    }
    if (b == NB - 1 && t == 0) off[N_NODES] = N_EDGES;
    __syncthreads();

    // scatter to node-sorted order (writes stay inside [s0,s1) = 16 KB window)
    for (int k = s0 + t; k < s1; k += 256) {
        unsigned p = binned[k];
        int n = (int)(p >> 24);
        int r = atomicAdd(&s_cur[n], 1);
        sorted_src[s0 + r] = (int)(p & 0xFFFFFFu);
    }
}

// ---------------------------------------------------------------------------
// K4: per-node aggregation + fused BN-stats.  8 threads/node (4 features
//     each), bf16 gather rows (64 B/edge), 8-wide ILP.
//     agg[n] = (h[n]*dis[n] + sum_{in(n)} h[s]*dis[s]) * dis[n]
// ---------------------------------------------------------------------------
__global__ void aggregate_kernel(const int* __restrict__ off,
                                 const int* __restrict__ sorted_src,
                                 const unsigned* __restrict__ hb,
                                 const float* __restrict__ dis,
                                 float* __restrict__ agg,
                                 float* __restrict__ stats) {
    int t = blockIdx.x * blockDim.x + threadIdx.x;
    int node = t >> 3;
    int c = t & 7;
    bool active = node < N_NODES;

    float4 ps = {0.f, 0.f, 0.f, 0.f};
    float4 pq = {0.f, 0.f, 0.f, 0.f};

    if (active) {
        const uint2* hrow = reinterpret_cast<const uint2*>(hb);
        float dn = dis[node];
        uint2 hp = hrow[(size_t)node * 8 + c];
        float4 a0, a1, a2, a3;
        a0.x = bflo(hp.x) * dn; a0.y = bfhi(hp.x) * dn;
        a0.z = bflo(hp.y) * dn; a0.w = bfhi(hp.y) * dn;
        a1 = a2 = a3 = make_float4(0.f, 0.f, 0.f, 0.f);

        int b = off[node], e = off[node + 1];
        int k = b;
        for (; k + 8 <= e; k += 8) {
            int s0 = sorted_src[k],     s1 = sorted_src[k + 1];
            int s2 = sorted_src[k + 2], s3 = sorted_src[k + 3];
            int s4 = sorted_src[k + 4], s5 = sorted_src[k + 5];
            int s6 = sorted_src[k + 6], s7 = sorted_src[k + 7];
            float d0 = dis[s0], d1 = dis[s1], d2 = dis[s2], d3 = dis[s3];
            float d4 = dis[s4], d5 = dis[s5], d6 = dis[s6], d7 = dis[s7];
            uint2 v0 = hrow[(size_t)s0 * 8 + c];
            uint2 v1 = hrow[(size_t)s1 * 8 + c];
            uint2 v2 = hrow[(size_t)s2 * 8 + c];
            uint2 v3 = hrow[(size_t)s3 * 8 + c];
            uint2 v4 = hrow[(size_t)s4 * 8 + c];
            uint2 v5 = hrow[(size_t)s5 * 8 + c];
            uint2 v6 = hrow[(size_t)s6 * 8 + c];
            uint2 v7 = hrow[(size_t)s7 * 8 + c];
            a0.x = fmaf(bflo(v0.x), d0, a0.x); a0.y = fmaf(bfhi(v0.x), d0, a0.y);
            a0.z = fmaf(bflo(v0.y), d0, a0.z); a0.w = fmaf(bfhi(v0.y), d0, a0.w);
            a1.x = fmaf(bflo(v1.x), d1, a1.x); a1.y = fmaf(bfhi(v1.x), d1, a1.y);
            a1.z = fmaf(bflo(v1.y), d1, a1.z); a1.w = fmaf(bfhi(v1.y), d1, a1.w);
            a2.x = fmaf(bflo(v2.x), d2, a2.x); a2.y = fmaf(bfhi(v2.x), d2, a2.y);
            a2.z = fmaf(bflo(v2.y), d2, a2.z); a2.w = fmaf(bfhi(v2.y), d2, a2.w);
            a3.x = fmaf(bflo(v3.x), d3, a3.x); a3.y = fmaf(bfhi(v3.x), d3, a3.y);
            a3.z = fmaf(bflo(v3.y), d3, a3.z); a3.w = fmaf(bfhi(v3.y), d3, a3.w);
            a0.x = fmaf(bflo(v4.x), d4, a0.x); a0.y = fmaf(bfhi(v4.x), d4, a0.y);
            a0.z = fmaf(bflo(v4.y), d4, a0.z); a0.w = fmaf(bfhi(v4.y), d4, a0.w);
            a1.x = fmaf(bflo(v5.x), d5, a1.x); a1.y = fmaf(bfhi(v5.x), d5, a1.y);
            a1.z = fmaf(bflo(v5.y), d5, a1.z); a1.w = fmaf(bfhi(v5.y), d5, a1.w);
            a2.x = fmaf(bflo(v6.x), d6, a2.x); a2.y = fmaf(bfhi(v6.x), d6, a2.y);
            a2.z = fmaf(bflo(v6.y), d6, a2.z); a2.w = fmaf(bfhi(v6.y), d6, a2.w);
            a3.x = fmaf(bflo(v7.x), d7, a3.x); a3.y = fmaf(bfhi(v7.x), d7, a3.y);
            a3.z = fmaf(bflo(v7.y), d7, a3.z); a3.w = fmaf(bfhi(v7.y), d7, a3.w);
        }
        for (; k < e; ++k) {
            int s = sorted_src[k];
            float d = dis[s];
            uint2 v = hrow[(size_t)s * 8 + c];
            a0.x = fmaf(bflo(v.x), d, a0.x); a0.y = fmaf(bfhi(v.x), d, a0.y);
            a0.z = fmaf(bflo(v.y), d, a0.z); a0.w = fmaf(bfhi(v.y), d, a0.w);
        }
        float4 o;
        o.x = (a0.x + a1.x + a2.x + a3.x) * dn;
        o.y = (a0.y + a1.y + a2.y + a3.y) * dn;
        o.z = (a0.z + a1.z + a2.z + a3.z) * dn;
        o.w = (a0.w + a1.w + a2.w + a3.w) * dn;
        reinterpret_cast<float4*>(agg)[(size_t)node * 8 + c] = o;
        ps = o;
        pq.x = o.x * o.x; pq.y = o.y * o.y; pq.z = o.z * o.z; pq.w = o.w * o.w;
    }

    // block-level stats reduce (all 256 threads reach barriers)
    __shared__ float S[256 * 4];
    __shared__ float Q[256 * 4];
    S[threadIdx.x * 4 + 0] = ps.x; S[threadIdx.x * 4 + 1] = ps.y;
    S[threadIdx.x * 4 + 2] = ps.z; S[threadIdx.x * 4 + 3] = ps.w;
    Q[threadIdx.x * 4 + 0] = pq.x; Q[threadIdx.x * 4 + 1] = pq.y;
    Q[threadIdx.x * 4 + 2] = pq.z; Q[threadIdx.x * 4 + 3] = pq.w;
    __syncthreads();
    if (threadIdx.x < 32) {
        int cc = threadIdx.x >> 2, j = threadIdx.x & 3;   // feature f = 4*cc+j
        float s = 0.0f, q = 0.0f;
#pragma unroll
        for (int w = 0; w < 32; ++w) {                    // threads with tid&7==cc
            int tid = (w << 3) | cc;
            s += S[tid * 4 + j];
            q += Q[tid * 4 + j];
        }
        float* rep = stats + 64 * (blockIdx.x & (NREP - 1));
        atomicAdd(&rep[threadIdx.x], s);
        atomicAdd(&rep[32 + threadIdx.x], q);
    }
}

// ---------------------------------------------------------------------------
// K5: out = relu(agg*A + B) @ W_cls + b_cls   (BN fold from NREP stat replicas)
// ---------------------------------------------------------------------------
__global__ void cls_kernel(const float* __restrict__ agg,
                           const float* __restrict__ stats,
                           const float* __restrict__ gamma,
                           const float* __restrict__ beta,
                           const float* __restrict__ W_cls,
                           const float* __restrict__ b_cls,
                           float* __restrict__ out) {
    __shared__ float sA[HID];
    __shared__ float sB[HID];
    __shared__ float sW[HID * N_CLS];
    __shared__ float sb[N_CLS];
    if (threadIdx.x < HID) {
        float sum = 0.0f, sq = 0.0f;
#pragma unroll
        for (int r = 0; r < NREP; ++r) {
            sum += stats[r * 64 + threadIdx.x];
            sq  += stats[r * 64 + 32 + threadIdx.x];
        }
        const float invN = 1.0f / (float)N_NODES;
        float mean = sum * invN;
        float var = sq * invN - mean * mean;
        float inv = rsqrtf(var + BN_EPS);
        float A = gamma[threadIdx.x] * inv;
        sA[threadIdx.x] = A;
        sB[threadIdx.x] = beta[threadIdx.x] - mean * A;
    }
    for (int t = threadIdx.x; t < HID * N_CLS; t += blockDim.x) sW[t] = W_cls[t];
    if (threadIdx.x < N_CLS) sb[threadIdx.x] = b_cls[threadIdx.x];
    __syncthreads();

    int i = blockIdx.x * blockDim.x + threadIdx.x;
    if (i >= N_NODES) return;

    float acc[N_CLS];
#pragma unroll
    for (int c = 0; c < N_CLS; ++c) acc[c] = sb[c];
#pragma unroll
    for (int f = 0; f < HID; ++f) {
        float t = fmaxf(fmaf(agg[(size_t)i * HID + f], sA[f], sB[f]), 0.0f);
#pragma unroll
        for (int c = 0; c < N_CLS; ++c) acc[c] = fmaf(t, sW[f * N_CLS + c], acc[c]);
    }
#pragma unroll
    for (int c = 0; c < N_CLS; ++c) out[(size_t)i * N_CLS + c] = acc[c];
}

// ---------------------------------------------------------------------------
extern "C" void kernel_launch(void* const* d_in, const int* in_sizes, int n_in,
                              void* d_out, int out_size, void* d_ws, size_t ws_size,
                              hipStream_t stream) {
    const float* x     = (const float*)d_in[0];
    const int*   edge  = (const int*)d_in[1];   // [2, E] int32
    const float* W_emb = (const float*)d_in[2];
    const float* b_emb = (const float*)d_in[3];
    const float* W_gcn = (const float*)d_in[4];
    // d_in[5] = b_gcn: per-feature constant, cancels exactly in BatchNorm -> skip
    const float* gamma = (const float*)d_in[6];
    const float* beta  = (const float*)d_in[7];
    const float* W_cls = (const float*)d_in[8];
    const float* b_cls = (const float*)d_in[9];
    float* out = (float*)d_out;

    // workspace layout (~49 MB)
    unsigned*     hb         = (unsigned*)d_ws;                 // N*HID/2 uints (bf16 x2)
    float*        agg        = (float*)(hb + (size_t)N_NODES * HID / 2);  // N*HID
    float*        dis        = agg + (size_t)N_NODES * HID;     // N
    int*          off        = (int*)(dis + N_NODES);           // N+1
    int*          bcnt       = off + N_NODES + 1;               // NB
    int*          boff       = bcnt + NB;                       // NB+1
    int*          bcur       = boff + NB + 1;                   // NB
    unsigned int* binned     = (unsigned int*)(bcur + NB);      // E
    int*          sorted_src = (int*)(binned + N_EDGES);        // E
    float*        stats      = (float*)(sorted_src + N_EDGES);  // 64*NREP

    hipMemsetAsync(bcnt, 0, NB * sizeof(int), stream);
    hipMemsetAsync(stats, 0, 64 * NREP * sizeof(float), stream);

    const int* src = edge;
    const int* dst = edge + N_EDGES;

    embed_hist_kernel<<<NBLK_EMB + NBLK_H, 256, 0, stream>>>(x, W_emb, b_emb, W_gcn,
                                                             hb, dst, bcnt);
    bucket_scan_kernel<<<1, 1024, 0, stream>>>(bcnt, boff, bcur);
    bin_edges_kernel<<<NBLK_BIN, 512, 0, stream>>>(src, dst, bcur, binned);
    bucket_csr_kernel<<<NB, 256, 0, stream>>>(boff, binned, sorted_src, off, dis);
    aggregate_kernel<<<(N_NODES * 8 + 255) / 256, 256, 0, stream>>>(off, sorted_src,
                                                                    hb, dis, agg, stats);
    cls_kernel<<<(N_NODES + 255) / 256, 256, 0, stream>>>(agg, stats, gamma, beta,
                                                          W_cls, b_cls, out);
}

// Round 9
// 150.982 us; speedup vs baseline: 1.4733x; 1.4733x over previous
//
#include <hip/hip_runtime.h>

#define N_NODES 150000
#define N_EDGES 2400000
#define F_IN    22
#define HID     32
#define N_CLS   6
#define BN_EPS  1e-5f

#define BSHIFT  8
#define BMASK   255
#define NB      ((N_NODES + BMASK) >> BSHIFT)       // 586 buckets of 256 nodes
#define NBLK_BIN 256                                // one bin block per CU
#define CHUNK   ((N_EDGES + NBLK_BIN - 1) / NBLK_BIN)   // 9375 edges per block
#define CHUNK_H 8192
#define NBLK_H  ((N_EDGES + CHUNK_H - 1) / CHUNK_H) // 293 hist blocks
#define NBLK_EMB ((N_NODES + 255) / 256)            // 586 embed blocks
#define NREP    8                                   // stats replicas

// bf16 round-to-nearest-even, packed storage helpers
__device__ __forceinline__ unsigned bf16rne(float f) {
    unsigned u = __float_as_uint(f);
    return (u + 0x7FFFu + ((u >> 16) & 1u)) >> 16;
}
__device__ __forceinline__ float bflo(unsigned p) { return __uint_as_float(p << 16); }
__device__ __forceinline__ float bfhi(unsigned p) { return __uint_as_float(p & 0xFFFF0000u); }

// ---------------------------------------------------------------------------
// K0 (fused): blocks [0,NBLK_EMB) -> per-node h = relu(x@W_emb+b_emb)@W_gcn,
//             stored as packed bf16 (16 uints per node row), written through
//             LDS so global stores are lane-contiguous (no partial-line RMW).
//             blocks [NBLK_EMB, NBLK_EMB+NBLK_H) -> bucket histogram of dst
// ---------------------------------------------------------------------------
__global__ void embed_hist_kernel(const float* __restrict__ x,
                                  const float* __restrict__ W_emb,
                                  const float* __restrict__ b_emb,
                                  const float* __restrict__ W_gcn,
                                  unsigned* __restrict__ hb,
                                  const int* __restrict__ dst,
                                  int* __restrict__ bcnt) {
    if (blockIdx.x < NBLK_EMB) {
        __shared__ float sWe[F_IN * HID];
        __shared__ float sbe[HID];
        __shared__ float sWg[HID * HID];
        __shared__ unsigned sp[256 * 17];   // packed rows, +1 pad (bank-safe)
        for (int t = threadIdx.x; t < F_IN * HID; t += blockDim.x) sWe[t] = W_emb[t];
        if (threadIdx.x < HID) sbe[threadIdx.x] = b_emb[threadIdx.x];
        for (int t = threadIdx.x; t < HID * HID; t += blockDim.x) sWg[t] = W_gcn[t];
        __syncthreads();

        int i = blockIdx.x * blockDim.x + threadIdx.x;
        bool act = i < N_NODES;

        if (act) {
            float xi[F_IN];
#pragma unroll
            for (int f = 0; f < F_IN; ++f) xi[f] = x[(size_t)i * F_IN + f];

            float h1[HID];
#pragma unroll
            for (int j = 0; j < HID; ++j) {
                float acc = sbe[j];
#pragma unroll
                for (int f = 0; f < F_IN; ++f) acc = fmaf(xi[f], sWe[f * HID + j], acc);
                h1[j] = fmaxf(acc, 0.0f);
            }
#pragma unroll
            for (int jj = 0; jj < HID / 2; ++jj) {
                float a0 = 0.0f, a1 = 0.0f;
#pragma unroll
                for (int f = 0; f < HID; ++f) {
                    a0 = fmaf(h1[f], sWg[f * HID + 2 * jj], a0);
                    a1 = fmaf(h1[f], sWg[f * HID + 2 * jj + 1], a1);
                }
                sp[threadIdx.x * 17 + jj] = bf16rne(a0) | (bf16rne(a1) << 16);
            }
        }
        __syncthreads();

        // cooperative coalesced write of the block's contiguous 16 KB region
        int nvalid = N_NODES - blockIdx.x * 256;
        if (nvalid > 256) nvalid = 256;
        int total = nvalid * 16;
        size_t gbase = (size_t)blockIdx.x * 256 * 16;
        for (int L = threadIdx.x; L < total; L += 256)
            hb[gbase + L] = sp[(L >> 4) * 17 + (L & 15)];
    } else {
        __shared__ int hloc[NB];
        for (int t = threadIdx.x; t < NB; t += 256) hloc[t] = 0;
        __syncthreads();
        int base = (blockIdx.x - NBLK_EMB) * CHUNK_H;
        int end = base + CHUNK_H; if (end > N_EDGES) end = N_EDGES;
        for (int i = base + threadIdx.x; i < end; i += 256)
            atomicAdd(&hloc[dst[i] >> BSHIFT], 1);
        __syncthreads();
        for (int t = threadIdx.x; t < NB; t += 256)
            if (hloc[t]) atomicAdd(&bcnt[t], hloc[t]);
    }
}

// ---------------------------------------------------------------------------
// K1: single-block exclusive scan of NB (=586) bucket counts -> boff, bcur
// ---------------------------------------------------------------------------
__global__ void bucket_scan_kernel(const int* __restrict__ bcnt,
                                   int* __restrict__ boff,
                                   int* __restrict__ bcur) {
    __shared__ int s[1024];
    int t = threadIdx.x;
    int v0 = (t < NB) ? bcnt[t] : 0;
    s[t] = v0;
    __syncthreads();
#pragma unroll
    for (int o = 1; o < 1024; o <<= 1) {
        int v = (t >= o) ? s[t - o] : 0;
        __syncthreads();
        s[t] += v;                 // inclusive
        __syncthreads();
    }
    if (t < NB) {
        int e = s[t] - v0;         // exclusive
        boff[t] = e;
        bcur[t] = e;
    }
    if (t == NB - 1) boff[NB] = s[t];   // == N_EDGES
}

// ---------------------------------------------------------------------------
// K2: binned append, 256 blocks (one per CU, balanced), 512 threads.
//     LDS hist of the chunk -> one global atomic per touched bucket to
//     reserve a range -> packed writes (~64 B runs per (block,bucket)).
//     packed = (dst & 255) << 24 | src   (src < 2^24)
// ---------------------------------------------------------------------------
__global__ void bin_edges_kernel(const int* __restrict__ src,
                                 const int* __restrict__ dst,
                                 int* __restrict__ bcur,
                                 unsigned int* __restrict__ binned) {
    __shared__ int hloc[NB];
    __shared__ int base[NB];
    __shared__ int lcur[NB];
    for (int t = threadIdx.x; t < NB; t += 512) hloc[t] = 0;
    __syncthreads();

    int cbase = blockIdx.x * CHUNK;
    int cend = cbase + CHUNK; if (cend > N_EDGES) cend = N_EDGES;
    for (int i = cbase + threadIdx.x; i < cend; i += 512)
        atomicAdd(&hloc[dst[i] >> BSHIFT], 1);
    __syncthreads();
    for (int t = threadIdx.x; t < NB; t += 512) {
        int c = hloc[t];
        base[t] = c ? atomicAdd(&bcur[t], c) : 0;
        lcur[t] = 0;
    }
    __syncthreads();
    for (int i = cbase + threadIdx.x; i < cend; i += 512) {
        int d = dst[i];
        int b = d >> BSHIFT;
        int r = atomicAdd(&lcur[b], 1);
        binned[base[b] + r] = ((unsigned)(d & BMASK) << 24) | (unsigned)src[i];
    }
}

// ---------------------------------------------------------------------------
// K3: per-bucket local counting sort -> fully dst-sorted sorted_src + off[],
//     plus dis = rsqrt(1+deg).  Writes stay in this bucket's 16 KB window.
// ---------------------------------------------------------------------------
__global__ void bucket_csr_kernel(const int* __restrict__ boff,
                                  const unsigned int* __restrict__ binned,
                                  int* __restrict__ sorted_src,
                                  int* __restrict__ off,
                                  float* __restrict__ dis) {
    __shared__ int s_cnt[256];
    __shared__ int s_scan[256];
    __shared__ int s_cur[256];
    int b = blockIdx.x;
    int t = threadIdx.x;
    int s0 = boff[b], s1 = boff[b + 1];
    int nbase = b << BSHIFT;
    int nnode = N_NODES - nbase; if (nnode > 256) nnode = 256;

    s_cnt[t] = 0;
    __syncthreads();
    for (int k = s0 + t; k < s1; k += 256)
        atomicAdd(&s_cnt[binned[k] >> 24], 1);
    __syncthreads();

    int v = s_cnt[t];
    s_scan[t] = v;
    __syncthreads();
#pragma unroll
    for (int o = 1; o < 256; o <<= 1) {
        int u = (t >= o) ? s_scan[t - o] : 0;
        __syncthreads();
        s_scan[t] += u;            // inclusive
        __syncthreads();
    }
    int excl = s_scan[t] - v;
    s_cur[t] = excl;
    if (t < nnode) {
        off[nbase + t] = s0 + excl;
        dis[nbase + t] = rsqrtf(1.0f + (float)v);
    }
    if (b == NB - 1 && t == 0) off[N_NODES] = N_EDGES;
    __syncthreads();

    // scatter to node-sorted order (writes stay inside [s0,s1) = 16 KB window)
    for (int k = s0 + t; k < s1; k += 256) {
        unsigned p = binned[k];
        int n = (int)(p >> 24);
        int r = atomicAdd(&s_cur[n], 1);
        sorted_src[s0 + r] = (int)(p & 0xFFFFFFu);
    }
}

// ---------------------------------------------------------------------------
// K4: per-node aggregation + fused BN-stats.  8 threads/node (4 features
//     each), bf16 gather rows (64 B/edge), 8-wide ILP.
//     agg[n] = (h[n]*dis[n] + sum_{in(n)} h[s]*dis[s]) * dis[n]
// ---------------------------------------------------------------------------
__global__ void aggregate_kernel(const int* __restrict__ off,
                                 const int* __restrict__ sorted_src,
                                 const unsigned* __restrict__ hb,
                                 const float* __restrict__ dis,
                                 float* __restrict__ agg,
                                 float* __restrict__ stats) {
    int t = blockIdx.x * blockDim.x + threadIdx.x;
    int node = t >> 3;
    int c = t & 7;
    bool active = node < N_NODES;

    float4 ps = {0.f, 0.f, 0.f, 0.f};
    float4 pq = {0.f, 0.f, 0.f, 0.f};

    if (active) {
        const uint2* hrow = reinterpret_cast<const uint2*>(hb);
        float dn = dis[node];
        uint2 hp = hrow[(size_t)node * 8 + c];
        float4 a0, a1, a2, a3;
        a0.x = bflo(hp.x) * dn; a0.y = bfhi(hp.x) * dn;
        a0.z = bflo(hp.y) * dn; a0.w = bfhi(hp.y) * dn;
        a1 = a2 = a3 = make_float4(0.f, 0.f, 0.f, 0.f);

        int b = off[node], e = off[node + 1];
        int k = b;
        for (; k + 8 <= e; k += 8) {
            int s0 = sorted_src[k],     s1 = sorted_src[k + 1];
            int s2 = sorted_src[k + 2], s3 = sorted_src[k + 3];
            int s4 = sorted_src[k + 4], s5 = sorted_src[k + 5];
            int s6 = sorted_src[k + 6], s7 = sorted_src[k + 7];
            float d0 = dis[s0], d1 = dis[s1], d2 = dis[s2], d3 = dis[s3];
            float d4 = dis[s4], d5 = dis[s5], d6 = dis[s6], d7 = dis[s7];
            uint2 v0 = hrow[(size_t)s0 * 8 + c];
            uint2 v1 = hrow[(size_t)s1 * 8 + c];
            uint2 v2 = hrow[(size_t)s2 * 8 + c];
            uint2 v3 = hrow[(size_t)s3 * 8 + c];
            uint2 v4 = hrow[(size_t)s4 * 8 + c];
            uint2 v5 = hrow[(size_t)s5 * 8 + c];
            uint2 v6 = hrow[(size_t)s6 * 8 + c];
            uint2 v7 = hrow[(size_t)s7 * 8 + c];
            a0.x = fmaf(bflo(v0.x), d0, a0.x); a0.y = fmaf(bfhi(v0.x), d0, a0.y);
            a0.z = fmaf(bflo(v0.y), d0, a0.z); a0.w = fmaf(bfhi(v0.y), d0, a0.w);
            a1.x = fmaf(bflo(v1.x), d1, a1.x); a1.y = fmaf(bfhi(v1.x), d1, a1.y);
            a1.z = fmaf(bflo(v1.y), d1, a1.z); a1.w = fmaf(bfhi(v1.y), d1, a1.w);
            a2.x = fmaf(bflo(v2.x), d2, a2.x); a2.y = fmaf(bfhi(v2.x), d2, a2.y);
            a2.z = fmaf(bflo(v2.y), d2, a2.z); a2.w = fmaf(bfhi(v2.y), d2, a2.w);
            a3.x = fmaf(bflo(v3.x), d3, a3.x); a3.y = fmaf(bfhi(v3.x), d3, a3.y);
            a3.z = fmaf(bflo(v3.y), d3, a3.z); a3.w = fmaf(bfhi(v3.y), d3, a3.w);
            a0.x = fmaf(bflo(v4.x), d4, a0.x); a0.y = fmaf(bfhi(v4.x), d4, a0.y);
            a0.z = fmaf(bflo(v4.y), d4, a0.z); a0.w = fmaf(bfhi(v4.y), d4, a0.w);
            a1.x = fmaf(bflo(v5.x), d5, a1.x); a1.y = fmaf(bfhi(v5.x), d5, a1.y);
            a1.z = fmaf(bflo(v5.y), d5, a1.z); a1.w = fmaf(bfhi(v5.y), d5, a1.w);
            a2.x = fmaf(bflo(v6.x), d6, a2.x); a2.y = fmaf(bfhi(v6.x), d6, a2.y);
            a2.z = fmaf(bflo(v6.y), d6, a2.z); a2.w = fmaf(bfhi(v6.y), d6, a2.w);
            a3.x = fmaf(bflo(v7.x), d7, a3.x); a3.y = fmaf(bfhi(v7.x), d7, a3.y);
            a3.z = fmaf(bflo(v7.y), d7, a3.z); a3.w = fmaf(bfhi(v7.y), d7, a3.w);
        }
        for (; k < e; ++k) {
            int s = sorted_src[k];
            float d = dis[s];
            uint2 v = hrow[(size_t)s * 8 + c];
            a0.x = fmaf(bflo(v.x), d, a0.x); a0.y = fmaf(bfhi(v.x), d, a0.y);
            a0.z = fmaf(bflo(v.y), d, a0.z); a0.w = fmaf(bfhi(v.y), d, a0.w);
        }
        float4 o;
        o.x = (a0.x + a1.x + a2.x + a3.x) * dn;
        o.y = (a0.y + a1.y + a2.y + a3.y) * dn;
        o.z = (a0.z + a1.z + a2.z + a3.z) * dn;
        o.w = (a0.w + a1.w + a2.w + a3.w) * dn;
        reinterpret_cast<float4*>(agg)[(size_t)node * 8 + c] = o;
        ps = o;
        pq.x = o.x * o.x; pq.y = o.y * o.y; pq.z = o.z * o.z; pq.w = o.w * o.w;
    }

    // block-level stats reduce (all 256 threads reach barriers)
    __shared__ float S[256 * 4];
    __shared__ float Q[256 * 4];
    S[threadIdx.x * 4 + 0] = ps.x; S[threadIdx.x * 4 + 1] = ps.y;
    S[threadIdx.x * 4 + 2] = ps.z; S[threadIdx.x * 4 + 3] = ps.w;
    Q[threadIdx.x * 4 + 0] = pq.x; Q[threadIdx.x * 4 + 1] = pq.y;
    Q[threadIdx.x * 4 + 2] = pq.z; Q[threadIdx.x * 4 + 3] = pq.w;
    __syncthreads();
    if (threadIdx.x < 32) {
        int cc = threadIdx.x >> 2, j = threadIdx.x & 3;   // feature f = 4*cc+j
        float s = 0.0f, q = 0.0f;
#pragma unroll
        for (int w = 0; w < 32; ++w) {                    // threads with tid&7==cc
            int tid = (w << 3) | cc;
            s += S[tid * 4 + j];
            q += Q[tid * 4 + j];
        }
        float* rep = stats + 64 * (blockIdx.x & (NREP - 1));
        atomicAdd(&rep[threadIdx.x], s);
        atomicAdd(&rep[32 + threadIdx.x], q);
    }
}

// ---------------------------------------------------------------------------
// K5: out = relu(agg*A + B) @ W_cls + b_cls   (BN fold from NREP stat replicas)
// ---------------------------------------------------------------------------
__global__ void cls_kernel(const float* __restrict__ agg,
                           const float* __restrict__ stats,
                           const float* __restrict__ gamma,
                           const float* __restrict__ beta,
                           const float* __restrict__ W_cls,
                           const float* __restrict__ b_cls,
                           float* __restrict__ out) {
    __shared__ float sA[HID];
    __shared__ float sB[HID];
    __shared__ float sW[HID * N_CLS];
    __shared__ float sb[N_CLS];
    if (threadIdx.x < HID) {
        float sum = 0.0f, sq = 0.0f;
#pragma unroll
        for (int r = 0; r < NREP; ++r) {
            sum += stats[r * 64 + threadIdx.x];
            sq  += stats[r * 64 + 32 + threadIdx.x];
        }
        const float invN = 1.0f / (float)N_NODES;
        float mean = sum * invN;
        float var = sq * invN - mean * mean;
        float inv = rsqrtf(var + BN_EPS);
        float A = gamma[threadIdx.x] * inv;
        sA[threadIdx.x] = A;
        sB[threadIdx.x] = beta[threadIdx.x] - mean * A;
    }
    for (int t = threadIdx.x; t < HID * N_CLS; t += blockDim.x) sW[t] = W_cls[t];
    if (threadIdx.x < N_CLS) sb[threadIdx.x] = b_cls[threadIdx.x];
    __syncthreads();

    int i = blockIdx.x * blockDim.x + threadIdx.x;
    if (i >= N_NODES) return;

    float acc[N_CLS];
#pragma unroll
    for (int c = 0; c < N_CLS; ++c) acc[c] = sb[c];
#pragma unroll
    for (int f = 0; f < HID; ++f) {
        float t = fmaxf(fmaf(agg[(size_t)i * HID + f], sA[f], sB[f]), 0.0f);
#pragma unroll
        for (int c = 0; c < N_CLS; ++c) acc[c] = fmaf(t, sW[f * N_CLS + c], acc[c]);
    }
#pragma unroll
    for (int c = 0; c < N_CLS; ++c) out[(size_t)i * N_CLS + c] = acc[c];
}

// ---------------------------------------------------------------------------
extern "C" void kernel_launch(void* const* d_in, const int* in_sizes, int n_in,
                              void* d_out, int out_size, void* d_ws, size_t ws_size,
                              hipStream_t stream) {
    const float* x     = (const float*)d_in[0];
    const int*   edge  = (const int*)d_in[1];   // [2, E] int32
    const float* W_emb = (const float*)d_in[2];
    const float* b_emb = (const float*)d_in[3];
    const float* W_gcn = (const float*)d_in[4];
    // d_in[5] = b_gcn: per-feature constant, cancels exactly in BatchNorm -> skip
    const float* gamma = (const float*)d_in[6];
    const float* beta  = (const float*)d_in[7];
    const float* W_cls = (const float*)d_in[8];
    const float* b_cls = (const float*)d_in[9];
    float* out = (float*)d_out;

    // workspace layout (~49 MB)
    unsigned*     hb         = (unsigned*)d_ws;                 // N*HID/2 uints (bf16 x2)
    float*        agg        = (float*)(hb + (size_t)N_NODES * HID / 2);  // N*HID
    float*        dis        = agg + (size_t)N_NODES * HID;     // N
    int*          off        = (int*)(dis + N_NODES);           // N+1
    int*          bcnt       = off + N_NODES + 1;               // NB
    int*          boff       = bcnt + NB;                       // NB+1
    int*          bcur       = boff + NB + 1;                   // NB
    unsigned int* binned     = (unsigned int*)(bcur + NB);      // E
    int*          sorted_src = (int*)(binned + N_EDGES);        // E
    float*        stats      = (float*)(sorted_src + N_EDGES);  // 64*NREP

    hipMemsetAsync(bcnt, 0, NB * sizeof(int), stream);
    hipMemsetAsync(stats, 0, 64 * NREP * sizeof(float), stream);

    const int* src = edge;
    const int* dst = edge + N_EDGES;

    embed_hist_kernel<<<NBLK_EMB + NBLK_H, 256, 0, stream>>>(x, W_emb, b_emb, W_gcn,
                                                             hb, dst, bcnt);
    bucket_scan_kernel<<<1, 1024, 0, stream>>>(bcnt, boff, bcur);
    bin_edges_kernel<<<NBLK_BIN, 512, 0, stream>>>(src, dst, bcur, binned);
    bucket_csr_kernel<<<NB, 256, 0, stream>>>(boff, binned, sorted_src, off, dis);
    aggregate_kernel<<<(N_NODES * 8 + 255) / 256, 256, 0, stream>>>(off, sorted_src,
                                                                    hb, dis, agg, stats);
    cls_kernel<<<(N_NODES + 255) / 256, 256, 0, stream>>>(agg, stats, gamma, beta,
                                                          W_cls, b_cls, out);
}

// Round 10
// 150.147 us; speedup vs baseline: 1.4814x; 1.0056x over previous
//
#include <hip/hip_runtime.h>

#define N_NODES 150000
#define N_EDGES 2400000
#define F_IN    22
#define HID     32
#define N_CLS   6
#define BN_EPS  1e-5f

#define BSHIFT  8
#define BMASK   255
#define NB      ((N_NODES + BMASK) >> BSHIFT)       // 586 buckets of 256 nodes
#define NBLK_BIN 256                                // one bin block per CU
#define CHUNK   ((N_EDGES + NBLK_BIN - 1) / NBLK_BIN)   // 9375 edges per block
#define CHUNK_H 8192
#define NBLK_H  ((N_EDGES + CHUNK_H - 1) / CHUNK_H) // 293 hist blocks
#define NBLK_EMB ((N_NODES + 255) / 256)            // 586 embed blocks
#define NREP    8                                   // stats replicas
#define XPAD    23                                  // padded x row stride in LDS

// bf16 round-to-nearest-even, packed storage helpers
__device__ __forceinline__ unsigned bf16rne(float f) {
    unsigned u = __float_as_uint(f);
    return (u + 0x7FFFu + ((u >> 16) & 1u)) >> 16;
}
__device__ __forceinline__ float bflo(unsigned p) { return __uint_as_float(p << 16); }
__device__ __forceinline__ float bfhi(unsigned p) { return __uint_as_float(p & 0xFFFF0000u); }

// ---------------------------------------------------------------------------
// K0 (fused): blocks [0,NBLK_EMB) -> per-node h = relu(x@W_emb+b_emb)@W_gcn,
//             x staged through LDS (coalesced global reads, 2-way-max bank
//             reads), result stored as packed bf16 via LDS (coalesced writes).
//             blocks [NBLK_EMB, NBLK_EMB+NBLK_H) -> bucket histogram of dst
// ---------------------------------------------------------------------------
__global__ void embed_hist_kernel(const float* __restrict__ x,
                                  const float* __restrict__ W_emb,
                                  const float* __restrict__ b_emb,
                                  const float* __restrict__ W_gcn,
                                  unsigned* __restrict__ hb,
                                  const int* __restrict__ dst,
                                  int* __restrict__ bcnt) {
    if (blockIdx.x < NBLK_EMB) {
        __shared__ float sWe[F_IN * HID];
        __shared__ float sbe[HID];
        __shared__ float sWg[HID * HID];
        __shared__ float sx[256 * XPAD];    // staged x rows, stride 23
        __shared__ unsigned sp[256 * 17];   // packed rows, +1 pad
        for (int t = threadIdx.x; t < F_IN * HID; t += blockDim.x) sWe[t] = W_emb[t];
        if (threadIdx.x < HID) sbe[threadIdx.x] = b_emb[threadIdx.x];
        for (int t = threadIdx.x; t < HID * HID; t += blockDim.x) sWg[t] = W_gcn[t];

        int nvalid = N_NODES - blockIdx.x * 256;
        if (nvalid > 256) nvalid = 256;

        // coalesced stage of this block's x rows into LDS
        {
            const float* xg = x + (size_t)blockIdx.x * 256 * F_IN;
            int totalx = nvalid * F_IN;
            for (int L = threadIdx.x; L < totalx; L += 256)
                sx[(L / F_IN) * XPAD + (L % F_IN)] = xg[L];
        }
        __syncthreads();

        bool act = threadIdx.x < nvalid;
        if (act) {
            float xi[F_IN];
#pragma unroll
            for (int f = 0; f < F_IN; ++f) xi[f] = sx[threadIdx.x * XPAD + f];

            float h1[HID];
#pragma unroll
            for (int j = 0; j < HID; ++j) {
                float acc = sbe[j];
#pragma unroll
                for (int f = 0; f < F_IN; ++f) acc = fmaf(xi[f], sWe[f * HID + j], acc);
                h1[j] = fmaxf(acc, 0.0f);
            }
#pragma unroll
            for (int jj = 0; jj < HID / 2; ++jj) {
                float a0 = 0.0f, a1 = 0.0f;
#pragma unroll
                for (int f = 0; f < HID; ++f) {
                    a0 = fmaf(h1[f], sWg[f * HID + 2 * jj], a0);
                    a1 = fmaf(h1[f], sWg[f * HID + 2 * jj + 1], a1);
                }
                sp[threadIdx.x * 17 + jj] = bf16rne(a0) | (bf16rne(a1) << 16);
            }
        }
        __syncthreads();

        // cooperative coalesced write of the block's contiguous 16 KB region
        int total = nvalid * 16;
        size_t gbase = (size_t)blockIdx.x * 256 * 16;
        for (int L = threadIdx.x; L < total; L += 256)
            hb[gbase + L] = sp[(L >> 4) * 17 + (L & 15)];
    } else {
        __shared__ int hloc[NB];
        for (int t = threadIdx.x; t < NB; t += 256) hloc[t] = 0;
        __syncthreads();
        int base = (blockIdx.x - NBLK_EMB) * CHUNK_H;
        int end = base + CHUNK_H; if (end > N_EDGES) end = N_EDGES;
        for (int i = base + threadIdx.x; i < end; i += 256)
            atomicAdd(&hloc[dst[i] >> BSHIFT], 1);
        __syncthreads();
        for (int t = threadIdx.x; t < NB; t += 256)
            if (hloc[t]) atomicAdd(&bcnt[t], hloc[t]);
    }
}

// ---------------------------------------------------------------------------
// K1: single-block exclusive scan of NB (=586) bucket counts -> boff, bcur
// ---------------------------------------------------------------------------
__global__ void bucket_scan_kernel(const int* __restrict__ bcnt,
                                   int* __restrict__ boff,
                                   int* __restrict__ bcur) {
    __shared__ int s[1024];
    int t = threadIdx.x;
    int v0 = (t < NB) ? bcnt[t] : 0;
    s[t] = v0;
    __syncthreads();
#pragma unroll
    for (int o = 1; o < 1024; o <<= 1) {
        int v = (t >= o) ? s[t - o] : 0;
        __syncthreads();
        s[t] += v;                 // inclusive
        __syncthreads();
    }
    if (t < NB) {
        int e = s[t] - v0;         // exclusive
        boff[t] = e;
        bcur[t] = e;
    }
    if (t == NB - 1) boff[NB] = s[t];   // == N_EDGES
}

// ---------------------------------------------------------------------------
// K2: binned append, 256 blocks (one per CU, balanced), 512 threads.
//     LDS hist of the chunk -> one global atomic per touched bucket to
//     reserve a range -> packed writes (~64 B runs per (block,bucket)).
//     packed = (dst & 255) << 24 | src   (src < 2^24)
// ---------------------------------------------------------------------------
__global__ void bin_edges_kernel(const int* __restrict__ src,
                                 const int* __restrict__ dst,
                                 int* __restrict__ bcur,
                                 unsigned int* __restrict__ binned) {
    __shared__ int hloc[NB];
    __shared__ int base[NB];
    __shared__ int lcur[NB];
    for (int t = threadIdx.x; t < NB; t += 512) hloc[t] = 0;
    __syncthreads();

    int cbase = blockIdx.x * CHUNK;
    int cend = cbase + CHUNK; if (cend > N_EDGES) cend = N_EDGES;
    for (int i = cbase + threadIdx.x; i < cend; i += 512)
        atomicAdd(&hloc[dst[i] >> BSHIFT], 1);
    __syncthreads();
    for (int t = threadIdx.x; t < NB; t += 512) {
        int c = hloc[t];
        base[t] = c ? atomicAdd(&bcur[t], c) : 0;
        lcur[t] = 0;
    }
    __syncthreads();
    for (int i = cbase + threadIdx.x; i < cend; i += 512) {
        int d = dst[i];
        int b = d >> BSHIFT;
        int r = atomicAdd(&lcur[b], 1);
        binned[base[b] + r] = ((unsigned)(d & BMASK) << 24) | (unsigned)src[i];
    }
}

// ---------------------------------------------------------------------------
// K3: per-bucket local counting sort -> fully dst-sorted sorted_src + off[],
//     plus dis = rsqrt(1+deg).  Writes stay in this bucket's 16 KB window.
// ---------------------------------------------------------------------------
__global__ void bucket_csr_kernel(const int* __restrict__ boff,
                                  const unsigned int* __restrict__ binned,
                                  int* __restrict__ sorted_src,
                                  int* __restrict__ off,
                                  float* __restrict__ dis) {
    __shared__ int s_cnt[256];
    __shared__ int s_scan[256];
    __shared__ int s_cur[256];
    int b = blockIdx.x;
    int t = threadIdx.x;
    int s0 = boff[b], s1 = boff[b + 1];
    int nbase = b << BSHIFT;
    int nnode = N_NODES - nbase; if (nnode > 256) nnode = 256;

    s_cnt[t] = 0;
    __syncthreads();
    for (int k = s0 + t; k < s1; k += 256)
        atomicAdd(&s_cnt[binned[k] >> 24], 1);
    __syncthreads();

    int v = s_cnt[t];
    s_scan[t] = v;
    __syncthreads();
#pragma unroll
    for (int o = 1; o < 256; o <<= 1) {
        int u = (t >= o) ? s_scan[t - o] : 0;
        __syncthreads();
        s_scan[t] += u;            // inclusive
        __syncthreads();
    }
    int excl = s_scan[t] - v;
    s_cur[t] = excl;
    if (t < nnode) {
        off[nbase + t] = s0 + excl;
        dis[nbase + t] = rsqrtf(1.0f + (float)v);
    }
    if (b == NB - 1 && t == 0) off[N_NODES] = N_EDGES;
    __syncthreads();

    // scatter to node-sorted order (writes stay inside [s0,s1) = 16 KB window)
    for (int k = s0 + t; k < s1; k += 256) {
        unsigned p = binned[k];
        int n = (int)(p >> 24);
        int r = atomicAdd(&s_cur[n], 1);
        sorted_src[s0 + r] = (int)(p & 0xFFFFFFu);
    }
}

// ---------------------------------------------------------------------------
// K4: per-node aggregation + fused BN-stats.  8 threads/node (4 features
//     each), bf16 gather rows (64 B/edge), 8-wide ILP.
//     agg[n] = (h[n]*dis[n] + sum_{in(n)} h[s]*dis[s]) * dis[n]
// ---------------------------------------------------------------------------
__global__ void aggregate_kernel(const int* __restrict__ off,
                                 const int* __restrict__ sorted_src,
                                 const unsigned* __restrict__ hb,
                                 const float* __restrict__ dis,
                                 float* __restrict__ agg,
                                 float* __restrict__ stats) {
    int t = blockIdx.x * blockDim.x + threadIdx.x;
    int node = t >> 3;
    int c = t & 7;
    bool active = node < N_NODES;

    float4 ps = {0.f, 0.f, 0.f, 0.f};
    float4 pq = {0.f, 0.f, 0.f, 0.f};

    if (active) {
        const uint2* hrow = reinterpret_cast<const uint2*>(hb);
        float dn = dis[node];
        uint2 hp = hrow[(size_t)node * 8 + c];
        float4 a0, a1, a2, a3;
        a0.x = bflo(hp.x) * dn; a0.y = bfhi(hp.x) * dn;
        a0.z = bflo(hp.y) * dn; a0.w = bfhi(hp.y) * dn;
        a1 = a2 = a3 = make_float4(0.f, 0.f, 0.f, 0.f);

        int b = off[node], e = off[node + 1];
        int k = b;
        for (; k + 8 <= e; k += 8) {
            int s0 = sorted_src[k],     s1 = sorted_src[k + 1];
            int s2 = sorted_src[k + 2], s3 = sorted_src[k + 3];
            int s4 = sorted_src[k + 4], s5 = sorted_src[k + 5];
            int s6 = sorted_src[k + 6], s7 = sorted_src[k + 7];
            float d0 = dis[s0], d1 = dis[s1], d2 = dis[s2], d3 = dis[s3];
            float d4 = dis[s4], d5 = dis[s5], d6 = dis[s6], d7 = dis[s7];
            uint2 v0 = hrow[(size_t)s0 * 8 + c];
            uint2 v1 = hrow[(size_t)s1 * 8 + c];
            uint2 v2 = hrow[(size_t)s2 * 8 + c];
            uint2 v3 = hrow[(size_t)s3 * 8 + c];
            uint2 v4 = hrow[(size_t)s4 * 8 + c];
            uint2 v5 = hrow[(size_t)s5 * 8 + c];
            uint2 v6 = hrow[(size_t)s6 * 8 + c];
            uint2 v7 = hrow[(size_t)s7 * 8 + c];
            a0.x = fmaf(bflo(v0.x), d0, a0.x); a0.y = fmaf(bfhi(v0.x), d0, a0.y);
            a0.z = fmaf(bflo(v0.y), d0, a0.z); a0.w = fmaf(bfhi(v0.y), d0, a0.w);
            a1.x = fmaf(bflo(v1.x), d1, a1.x); a1.y = fmaf(bfhi(v1.x), d1, a1.y);
            a1.z = fmaf(bflo(v1.y), d1, a1.z); a1.w = fmaf(bfhi(v1.y), d1, a1.w);
            a2.x = fmaf(bflo(v2.x), d2, a2.x); a2.y = fmaf(bfhi(v2.x), d2, a2.y);
            a2.z = fmaf(bflo(v2.y), d2, a2.z); a2.w = fmaf(bfhi(v2.y), d2, a2.w);
            a3.x = fmaf(bflo(v3.x), d3, a3.x); a3.y = fmaf(bfhi(v3.x), d3, a3.y);
            a3.z = fmaf(bflo(v3.y), d3, a3.z); a3.w = fmaf(bfhi(v3.y), d3, a3.w);
            a0.x = fmaf(bflo(v4.x), d4, a0.x); a0.y = fmaf(bfhi(v4.x), d4, a0.y);
            a0.z = fmaf(bflo(v4.y), d4, a0.z); a0.w = fmaf(bfhi(v4.y), d4, a0.w);
            a1.x = fmaf(bflo(v5.x), d5, a1.x); a1.y = fmaf(bfhi(v5.x), d5, a1.y);
            a1.z = fmaf(bflo(v5.y), d5, a1.z); a1.w = fmaf(bfhi(v5.y), d5, a1.w);
            a2.x = fmaf(bflo(v6.x), d6, a2.x); a2.y = fmaf(bfhi(v6.x), d6, a2.y);
            a2.z = fmaf(bflo(v6.y), d6, a2.z); a2.w = fmaf(bfhi(v6.y), d6, a2.w);
            a3.x = fmaf(bflo(v7.x), d7, a3.x); a3.y = fmaf(bfhi(v7.x), d7, a3.y);
            a3.z = fmaf(bflo(v7.y), d7, a3.z); a3.w = fmaf(bfhi(v7.y), d7, a3.w);
        }
        for (; k < e; ++k) {
            int s = sorted_src[k];
            float d = dis[s];
            uint2 v = hrow[(size_t)s * 8 + c];
            a0.x = fmaf(bflo(v.x), d, a0.x); a0.y = fmaf(bfhi(v.x), d, a0.y);
            a0.z = fmaf(bflo(v.y), d, a0.z); a0.w = fmaf(bfhi(v.y), d, a0.w);
        }
        float4 o;
        o.x = (a0.x + a1.x + a2.x + a3.x) * dn;
        o.y = (a0.y + a1.y + a2.y + a3.y) * dn;
        o.z = (a0.z + a1.z + a2.z + a3.z) * dn;
        o.w = (a0.w + a1.w + a2.w + a3.w) * dn;
        reinterpret_cast<float4*>(agg)[(size_t)node * 8 + c] = o;
        ps = o;
        pq.x = o.x * o.x; pq.y = o.y * o.y; pq.z = o.z * o.z; pq.w = o.w * o.w;
    }

    // block-level stats reduce (all 256 threads reach barriers)
    __shared__ float S[256 * 4];
    __shared__ float Q[256 * 4];
    S[threadIdx.x * 4 + 0] = ps.x; S[threadIdx.x * 4 + 1] = ps.y;
    S[threadIdx.x * 4 + 2] = ps.z; S[threadIdx.x * 4 + 3] = ps.w;
    Q[threadIdx.x * 4 + 0] = pq.x; Q[threadIdx.x * 4 + 1] = pq.y;
    Q[threadIdx.x * 4 + 2] = pq.z; Q[threadIdx.x * 4 + 3] = pq.w;
    __syncthreads();
    if (threadIdx.x < 32) {
        int cc = threadIdx.x >> 2, j = threadIdx.x & 3;   // feature f = 4*cc+j
        float s = 0.0f, q = 0.0f;
#pragma unroll
        for (int w = 0; w < 32; ++w) {                    // threads with tid&7==cc
            int tid = (w << 3) | cc;
            s += S[tid * 4 + j];
            q += Q[tid * 4 + j];
        }
        float* rep = stats + 64 * (blockIdx.x & (NREP - 1));
        atomicAdd(&rep[threadIdx.x], s);
        atomicAdd(&rep[32 + threadIdx.x], q);
    }
}

// ---------------------------------------------------------------------------
// K5: out = relu(agg*A + B) @ W_cls + b_cls   (BN fold from NREP stat replicas)
// ---------------------------------------------------------------------------
__global__ void cls_kernel(const float* __restrict__ agg,
                           const float* __restrict__ stats,
                           const float* __restrict__ gamma,
                           const float* __restrict__ beta,
                           const float* __restrict__ W_cls,
                           const float* __restrict__ b_cls,
                           float* __restrict__ out) {
    __shared__ float sA[HID];
    __shared__ float sB[HID];
    __shared__ float sW[HID * N_CLS];
    __shared__ float sb[N_CLS];
    if (threadIdx.x < HID) {
        float sum = 0.0f, sq = 0.0f;
#pragma unroll
        for (int r = 0; r < NREP; ++r) {
            sum += stats[r * 64 + threadIdx.x];
            sq  += stats[r * 64 + 32 + threadIdx.x];
        }
        const float invN = 1.0f / (float)N_NODES;
        float mean = sum * invN;
        float var = sq * invN - mean * mean;
        float inv = rsqrtf(var + BN_EPS);
        float A = gamma[threadIdx.x] * inv;
        sA[threadIdx.x] = A;
        sB[threadIdx.x] = beta[threadIdx.x] - mean * A;
    }
    for (int t = threadIdx.x; t < HID * N_CLS; t += blockDim.x) sW[t] = W_cls[t];
    if (threadIdx.x < N_CLS) sb[threadIdx.x] = b_cls[threadIdx.x];
    __syncthreads();

    int i = blockIdx.x * blockDim.x + threadIdx.x;
    if (i >= N_NODES) return;

    float acc[N_CLS];
#pragma unroll
    for (int c = 0; c < N_CLS; ++c) acc[c] = sb[c];
#pragma unroll
    for (int f = 0; f < HID; ++f) {
        float t = fmaxf(fmaf(agg[(size_t)i * HID + f], sA[f], sB[f]), 0.0f);
#pragma unroll
        for (int c = 0; c < N_CLS; ++c) acc[c] = fmaf(t, sW[f * N_CLS + c], acc[c]);
    }
#pragma unroll
    for (int c = 0; c < N_CLS; ++c) out[(size_t)i * N_CLS + c] = acc[c];
}

// ---------------------------------------------------------------------------
extern "C" void kernel_launch(void* const* d_in, const int* in_sizes, int n_in,
                              void* d_out, int out_size, void* d_ws, size_t ws_size,
                              hipStream_t stream) {
    const float* x     = (const float*)d_in[0];
    const int*   edge  = (const int*)d_in[1];   // [2, E] int32
    const float* W_emb = (const float*)d_in[2];
    const float* b_emb = (const float*)d_in[3];
    const float* W_gcn = (const float*)d_in[4];
    // d_in[5] = b_gcn: per-feature constant, cancels exactly in BatchNorm -> skip
    const float* gamma = (const float*)d_in[6];
    const float* beta  = (const float*)d_in[7];
    const float* W_cls = (const float*)d_in[8];
    const float* b_cls = (const float*)d_in[9];
    float* out = (float*)d_out;

    // workspace layout (~49 MB)
    unsigned*     hb         = (unsigned*)d_ws;                 // N*HID/2 uints (bf16 x2)
    float*        agg        = (float*)(hb + (size_t)N_NODES * HID / 2);  // N*HID
    float*        dis        = agg + (size_t)N_NODES * HID;     // N
    int*          off        = (int*)(dis + N_NODES);           // N+1
    int*          bcnt       = off + N_NODES + 1;               // NB
    int*          boff       = bcnt + NB;                       // NB+1
    int*          bcur       = boff + NB + 1;                   // NB
    unsigned int* binned     = (unsigned int*)(bcur + NB);      // E
    int*          sorted_src = (int*)(binned + N_EDGES);        // E
    float*        stats      = (float*)(sorted_src + N_EDGES);  // 64*NREP

    hipMemsetAsync(bcnt, 0, NB * sizeof(int), stream);
    hipMemsetAsync(stats, 0, 64 * NREP * sizeof(float), stream);

    const int* src = edge;
    const int* dst = edge + N_EDGES;

    embed_hist_kernel<<<NBLK_EMB + NBLK_H, 256, 0, stream>>>(x, W_emb, b_emb, W_gcn,
                                                             hb, dst, bcnt);
    bucket_scan_kernel<<<1, 1024, 0, stream>>>(bcnt, boff, bcur);
    bin_edges_kernel<<<NBLK_BIN, 512, 0, stream>>>(src, dst, bcur, binned);
    bucket_csr_kernel<<<NB, 256, 0, stream>>>(boff, binned, sorted_src, off, dis);
    aggregate_kernel<<<(N_NODES * 8 + 255) / 256, 256, 0, stream>>>(off, sorted_src,
                                                                    hb, dis, agg, stats);
    cls_kernel<<<(N_NODES + 255) / 256, 256, 0, stream>>>(agg, stats, gamma, beta,
                                                          W_cls, b_cls, out);
}